// Round 3
// baseline (367.047 us; speedup 1.0000x reference)
//
#include <hip/hip_runtime.h>

// Problem constants (fixed by reference setup_inputs)
#define B   4
#define C   64      // input channels
#define D   64      // dims per head of q/k/v
#define NN  25      // angRes*angRes angular positions
#define HW  4096    // h*w
#define F   (D*HW)  // 262144 feature dim (d,h,w) flattened

#define SW  256     // f elems per wave in k_sqk (4 waves/block) -> 1024 blocks
#define PT  64      // p-tile per block in k_qkmfma / k_vproj (16KB LDS -> 8 blocks/CU)

typedef unsigned short ushort_t;
typedef unsigned int   uint_t;
typedef __attribute__((ext_vector_type(8)))  short  short8;   // 8 bf16 (4 VGPRs)
typedef __attribute__((ext_vector_type(16))) float  floatx16; // MFMA 32x32 accum
typedef __attribute__((ext_vector_type(4)))  float  f32x4;
typedef __attribute__((ext_vector_type(4)))  unsigned short us4;

// Compensated bf16 weight splits (W = hi + lo, |err| ~ 2^-17 rel), native
// [row][c] layout. Rows 0..127 = q,k; rows 0..63 of Wv = v.
__device__ ushort_t g_Wthi[128 * C];
__device__ ushort_t g_Wtlo[128 * C];
__device__ ushort_t g_Wvhi[D * C];
__device__ ushort_t g_Wvlo[D * C];

static __device__ __forceinline__ ushort_t f2bf(float f) {
    uint_t u = __float_as_uint(f);
    u += 0x7FFFu + ((u >> 16) & 1u);   // round-to-nearest-even
    return (ushort_t)(u >> 16);
}
static __device__ __forceinline__ float bf2f(ushort_t h) {
    return __uint_as_float((uint_t)h << 16);
}

// LDS elem index for transposed tile xT[p][c] (bf16, PT=64 rows of 64 c).
// 8-c granules XOR'd by (p>>2)&7: ds_read_b128 of 8 contig c stays intact,
// banks spread across the 8 granule slots (measured ~4-way residual, ~3.6%
// of cycles at round-2 sizes -> acceptable).
static __device__ __forceinline__ int lds_x(int p, int c) {
    return p * 64 + ((((c >> 3) ^ ((p >> 2) & 7)) << 3) | (c & 7));
}

// ---- K0: zero the S/qq/kk accumulators (they live at head of d_out) ----
__global__ void k_zero(float* acc) {
    int i = blockIdx.x * 256 + threadIdx.x;
    if (i < 2700) acc[i] = 0.f;   // S 2500 + qq 100 + kk 100
}

// ---- Kw: split all 192 W rows into bf16 hi/lo (native layout). ----
__global__ void k_wprep(const float* __restrict__ W) {
    int i = blockIdx.x * 256 + threadIdx.x;          // over 192*64
    if (i < 128 * 64) {
        float w = W[i];                              // W[d'][c], native index
        ushort_t hi = f2bf(w);
        g_Wthi[i] = hi;
        g_Wtlo[i] = f2bf(w - bf2f(hi));
    } else if (i < 192 * 64) {
        float w = W[i];                              // v rows 128..191
        int j = i - 128 * 64;
        ushort_t hi = f2bf(w);
        g_Wvhi[j] = hi;
        g_Wvlo[j] = f2bf(w - bf2f(hi));
    }
}

// ---- K1: Q,K projection via compensated-bf16 MFMA + fused norms.
// grid (HW/PT, NN, B), 256 thr = 4 waves, 16KB LDS, launch_bounds(256,8)
// -> 8 blocks/CU (32 waves/CU): inter-block overlap hides stage latency
// (round-2 ran 2 blocks/CU and idled 77% of cycles). Wave wv owns the
// 32-row d'-slab d0=wv*32 of [Q;K]; per wave 2 p-tiles x 4 ks x 3 hi/lo
// combos = 24 MFMA. Result == fp32 projection to ~2^-17, then f2bf.
__global__ void __launch_bounds__(256, 8)
k_qkmfma(const float* __restrict__ x,
         ushort_t* __restrict__ Q, ushort_t* __restrict__ K,
         float* __restrict__ qq, float* __restrict__ kk) {
    __shared__ ushort_t sXhi[PT * 64];
    __shared__ ushort_t sXlo[PT * 64];

    const int t  = threadIdx.x;
    const int wv = t >> 6, ln = t & 63;
    const int n  = blockIdx.y, b = blockIdx.z;
    const int gp0 = blockIdx.x * PT;

    // ---- stage: wave wv loads c in [wv*16, wv*16+16) for all PT p,
    // converts to hi/lo, writes transposed into LDS.
    {
        const int c16 = wv * 16;
#pragma unroll
        for (int cg = 0; cg < 4; ++cg) {
            const int c4 = c16 + cg * 4;
            const float* xc = x + ((size_t)(b * C + c4) * NN + n) * HW + gp0;
            float v[4];
#pragma unroll
            for (int i = 0; i < 4; ++i) v[i] = xc[(size_t)i * NN * HW + ln];
            us4 h, l;
#pragma unroll
            for (int i = 0; i < 4; ++i) {
                ushort_t hi = f2bf(v[i]);
                h[i] = hi;
                l[i] = f2bf(v[i] - bf2f(hi));
            }
            *(us4*)&sXhi[lds_x(ln, c4)] = h;
            *(us4*)&sXlo[lds_x(ln, c4)] = l;
        }
    }
    __syncthreads();

    // ---- A fragments: W rows d0..d0+31, from global (L1/L2-hot, tiny).
    const int row = ln & 31, kh = (ln >> 5) * 8, d0 = wv * 32;
    short8 ahi[4], alo[4];
#pragma unroll
    for (int ks = 0; ks < 4; ++ks) {
        ahi[ks] = *(const short8*)&g_Wthi[(d0 + row) * 64 + ks * 16 + kh];
        alo[ks] = *(const short8*)&g_Wtlo[(d0 + row) * 64 + ks * 16 + kh];
    }

    ushort_t* __restrict__ O = (wv < 2) ? Q : K;
    const int dbase = (wv < 2) ? d0 : (d0 - 64);
    const size_t obase = ((size_t)(b * NN + n) * D + dbase) * HW + gp0;

    float nrm = 0.f;
#pragma unroll
    for (int pt = 0; pt < 2; ++pt) {
        const int pcol = pt * 32 + row;
        floatx16 acc;
#pragma unroll
        for (int r = 0; r < 16; ++r) acc[r] = 0.f;
#pragma unroll
        for (int ks = 0; ks < 4; ++ks) {
            const int c0 = ks * 16 + kh;
            short8 bhi = *(const short8*)&sXhi[lds_x(pcol, c0)];
            short8 blo = *(const short8*)&sXlo[lds_x(pcol, c0)];
            acc = __builtin_amdgcn_mfma_f32_32x32x16_bf16(ahi[ks], bhi, acc, 0, 0, 0);
            acc = __builtin_amdgcn_mfma_f32_32x32x16_bf16(alo[ks], bhi, acc, 0, 0, 0);
            acc = __builtin_amdgcn_mfma_f32_32x32x16_bf16(ahi[ks], blo, acc, 0, 0, 0);
        }
        // C/D layout (m74/m101): col = ln&31, row = (r&3)+8*(r>>2)+4*(ln>>5)
#pragma unroll
        for (int r = 0; r < 16; ++r) {
            const int dr = (r & 3) + 8 * (r >> 2) + 4 * (ln >> 5);
            nrm += acc[r] * acc[r];
            O[obase + (size_t)dr * HW + pcol] = f2bf(acc[r]);
        }
    }
    for (int off = 32; off > 0; off >>= 1) nrm += __shfl_xor(nrm, off);
    if (ln == 0) atomicAdd(((wv < 2) ? qq : kk) + b * NN + n, nrm);
}

// ---- K2: S[n][m] += sum_f Q[n,f]*K[m,f] via one 32x32x16 bf16 MFMA tile.
// grid (F/(4*SW), B), 256 thr = 4 waves, each wave owns SW f-elems.
__global__ void k_sqk(const ushort_t* __restrict__ Q, const ushort_t* __restrict__ K,
                      float* __restrict__ S) {
    const int t  = threadIdx.x;
    const int wv = t >> 6, ln = t & 63;
    const int b  = blockIdx.y;
    const int row  = ln & 31;
    const int rowc = (row < NN) ? row : (NN - 1);   // clamp pad rows
    const int kh   = (ln >> 5) * 8;                 // k-half offset
    const size_t f0 = (size_t)blockIdx.x * (4 * SW) + (size_t)wv * SW;
    const ushort_t* Qp = Q + ((size_t)b * NN + rowc) * F + f0 + kh;
    const ushort_t* Kp = K + ((size_t)b * NN + rowc) * F + f0 + kh;

    floatx16 acc;
#pragma unroll
    for (int r = 0; r < 16; ++r) acc[r] = 0.f;

    for (int s = 0; s < SW / 16; ++s) {
        short8 aq = *(const short8*)(Qp + s * 16);  // A[row][k] : 8 contig bf16
        short8 bk = *(const short8*)(Kp + s * 16);  // B[k][col] : K row 'col'
        acc = __builtin_amdgcn_mfma_f32_32x32x16_bf16(aq, bk, acc, 0, 0, 0);
    }

    // cross-wave reduce in LDS (stride 17 -> conflict-free), then atomics
    __shared__ float redS[4][64][17];
#pragma unroll
    for (int r = 0; r < 16; ++r) redS[wv][ln][r] = acc[r];
    __syncthreads();
    if (wv == 0) {
#pragma unroll
        for (int r = 0; r < 16; ++r) {
            float v = redS[0][ln][r] + redS[1][ln][r] + redS[2][ln][r] + redS[3][ln][r];
            const int srow = (r & 3) + 8 * (r >> 2) + 4 * (ln >> 5); // C/D: m74/m101
            const int scol = ln & 31;
            if (srow < NN && scol < NN)
                atomicAdd(&S[((size_t)b * NN + srow) * NN + scol], v);
        }
    }
}

// ---- K3: normalize logits + softmax over m; writes TRANSPOSED att.
__global__ void k_softmax(const float* __restrict__ S, const float* __restrict__ qq,
                          const float* __restrict__ kk, float* __restrict__ attT) {
    const int b = blockIdx.x, n = threadIdx.x;
    if (n >= NN) return;
    const float qn = fmaxf(sqrtf(qq[b * NN + n]), 1e-12f);
    float l[NN], mx = -1e30f;
#pragma unroll
    for (int m = 0; m < NN; ++m) {
        const float km = fmaxf(sqrtf(kk[b * NN + m]), 1e-12f);
        l[m] = S[((size_t)b * NN + n) * NN + m] / (qn * km);
        mx = fmaxf(mx, l[m]);
    }
    float s = 0.f;
#pragma unroll
    for (int m = 0; m < NN; ++m) { l[m] = expf(l[m] - mx); s += l[m]; }
    const float inv = 1.f / s;
#pragma unroll
    for (int m = 0; m < NN; ++m) attT[((size_t)b * NN + m) * NN + n] = l[m] * inv;
}

// ---- K4a: xa[b,c,n,p] = sum_m att[n,m] * x[b,c,m,p], f32x4 form.
// grid (HW/1024, C, B) = 1024 blocks (4/CU resident). 4 p per thread:
// 4 FMA per loaded element (was 1), acc = 25 x f32x4 = 100 VGPR.
__global__ void __launch_bounds__(256, 4)
k_mix(const float* __restrict__ x, const float* __restrict__ attT,
      float* __restrict__ xa) {
    const int p = (blockIdx.x * 256 + threadIdx.x) * 4;
    const int c = blockIdx.y, b = blockIdx.z;
    const float* xb = x + ((size_t)(b * C + c) * NN) * HW + p;
    const float* at = attT + (size_t)b * NN * NN;
    f32x4 acc[NN];
#pragma unroll
    for (int n = 0; n < NN; ++n) acc[n] = 0.f;
#pragma unroll 5
    for (int m = 0; m < NN; ++m) {
        const f32x4 xm = *(const f32x4*)(xb + (size_t)m * HW);
#pragma unroll
        for (int n = 0; n < NN; ++n) acc[n] += at[m * NN + n] * xm; // contig s_load
    }
#pragma unroll
    for (int n = 0; n < NN; ++n)
        *(f32x4*)&xa[((size_t)(b * C + c) * NN + n) * HW + p] = acc[n];
}

// ---- K4b: out[b,d,n,p] = sum_c Wv[d,c]*xa[b,c,n,p] via compensated MFMA.
// Exact clone of k_qkmfma's structure (stage xa -> hi/lo LDS -> 3-pass
// MFMA with Wv hi/lo, err ~2^-17). Waves: (wv&1) picks d-slab 0/32,
// (wv>>1) picks p-half. 12 MFMA/wave. 16KB LDS -> 8 blocks/CU.
__global__ void __launch_bounds__(256, 8)
k_vproj(const float* __restrict__ xa, float* __restrict__ out) {
    __shared__ ushort_t sXhi[PT * 64];
    __shared__ ushort_t sXlo[PT * 64];

    const int t  = threadIdx.x;
    const int wv = t >> 6, ln = t & 63;
    const int n  = blockIdx.y, b = blockIdx.z;
    const int gp0 = blockIdx.x * PT;

    {
        const int c16 = wv * 16;
#pragma unroll
        for (int cg = 0; cg < 4; ++cg) {
            const int c4 = c16 + cg * 4;
            const float* xc = xa + ((size_t)(b * C + c4) * NN + n) * HW + gp0;
            float v[4];
#pragma unroll
            for (int i = 0; i < 4; ++i) v[i] = xc[(size_t)i * NN * HW + ln];
            us4 h, l;
#pragma unroll
            for (int i = 0; i < 4; ++i) {
                ushort_t hi = f2bf(v[i]);
                h[i] = hi;
                l[i] = f2bf(v[i] - bf2f(hi));
            }
            *(us4*)&sXhi[lds_x(ln, c4)] = h;
            *(us4*)&sXlo[lds_x(ln, c4)] = l;
        }
    }
    __syncthreads();

    const int row = ln & 31, kh = (ln >> 5) * 8;
    const int d0  = (wv & 1) * 32;
    short8 ahi[4], alo[4];
#pragma unroll
    for (int ks = 0; ks < 4; ++ks) {
        ahi[ks] = *(const short8*)&g_Wvhi[(d0 + row) * 64 + ks * 16 + kh];
        alo[ks] = *(const short8*)&g_Wvlo[(d0 + row) * 64 + ks * 16 + kh];
    }

    const int pcol = (wv >> 1) * 32 + row;
    floatx16 acc;
#pragma unroll
    for (int r = 0; r < 16; ++r) acc[r] = 0.f;
#pragma unroll
    for (int ks = 0; ks < 4; ++ks) {
        const int c0 = ks * 16 + kh;
        short8 bhi = *(const short8*)&sXhi[lds_x(pcol, c0)];
        short8 blo = *(const short8*)&sXlo[lds_x(pcol, c0)];
        acc = __builtin_amdgcn_mfma_f32_32x32x16_bf16(ahi[ks], bhi, acc, 0, 0, 0);
        acc = __builtin_amdgcn_mfma_f32_32x32x16_bf16(alo[ks], bhi, acc, 0, 0, 0);
        acc = __builtin_amdgcn_mfma_f32_32x32x16_bf16(ahi[ks], blo, acc, 0, 0, 0);
    }
#pragma unroll
    for (int r = 0; r < 16; ++r) {
        const int dr = (r & 3) + 8 * (r >> 2) + 4 * (ln >> 5);
        out[((size_t)(b * D + d0 + dr) * NN + n) * HW + gp0 + pcol] = acc[r];
    }
}

extern "C" void kernel_launch(void* const* d_in, const int* in_sizes, int n_in,
                              void* d_out, int out_size, void* d_ws, size_t ws_size,
                              hipStream_t stream) {
    const float* x = (const float*)d_in[0];
    const float* W = (const float*)d_in[1];
    float* outf = (float*)d_out;

    // ws: [ Q bf16 52.4MB | K bf16 52.4MB ], later reused as xa fp32 (104.86MB)
    ushort_t* Q  = (ushort_t*)d_ws;
    ushort_t* K  = Q + (size_t)B * NN * F;
    float*    xa = (float*)d_ws;

    // tiny accumulators live at head of d_out (dead until k_vproj rewrites all)
    float* S    = outf;          // 4*25*25
    float* qq   = outf + 2500;   // 4*25
    float* kk   = outf + 2600;   // 4*25
    float* attT = outf + 2700;   // 4*25*25 (transposed: [b][m][n])

    k_zero   <<<dim3(11),             256, 0, stream>>>(outf);
    k_wprep  <<<dim3(48),             256, 0, stream>>>(W);
    k_qkmfma <<<dim3(HW/PT, NN, B),   256, 0, stream>>>(x, Q, K, qq, kk);
    k_sqk    <<<dim3(F/(4*SW), B),    256, 0, stream>>>(Q, K, S);
    k_softmax<<<dim3(B),               64, 0, stream>>>(S, qq, kk, attT);
    k_mix    <<<dim3(HW/1024, C, B),  256, 0, stream>>>(x, attT, xa);
    k_vproj  <<<dim3(HW/PT, NN, B),   256, 0, stream>>>(xa, outf);
}

// Round 4
// 315.599 us; speedup vs baseline: 1.1630x; 1.1630x over previous
//
#include <hip/hip_runtime.h>

// Problem constants (fixed by reference setup_inputs)
#define B   4
#define C   64      // input channels
#define D   64      // dims per head of q/k/v
#define NN  25      // angRes*angRes angular positions
#define HW  4096    // h*w
#define F   (D*HW)  // 262144 feature dim (d,h,w) flattened

#define SW  256     // f elems per wave in k_sqk (4 waves/block) -> 1024 blocks
#define PT  128     // p-tile per block in k_qkmfma / k_vproj (32KB LDS, 4 blk/CU)

typedef unsigned short ushort_t;
typedef unsigned int   uint_t;
typedef __attribute__((ext_vector_type(8)))  short  short8;   // 8 bf16 (4 VGPRs)
typedef __attribute__((ext_vector_type(16))) float  floatx16; // MFMA 32x32 accum
typedef __attribute__((ext_vector_type(4)))  float  f32x4;
typedef __attribute__((ext_vector_type(4)))  unsigned short us4;

// Compensated bf16 weight splits (W = hi + lo, |err| ~ 2^-17 rel), native
// [row][c] layout. Rows 0..127 = q,k; rows 0..63 of Wv = v.
__device__ ushort_t g_Wthi[128 * C];
__device__ ushort_t g_Wtlo[128 * C];
__device__ ushort_t g_Wvhi[D * C];
__device__ ushort_t g_Wvlo[D * C];

static __device__ __forceinline__ ushort_t f2bf(float f) {
    uint_t u = __float_as_uint(f);
    u += 0x7FFFu + ((u >> 16) & 1u);   // round-to-nearest-even
    return (ushort_t)(u >> 16);
}
static __device__ __forceinline__ float bf2f(ushort_t h) {
    return __uint_as_float((uint_t)h << 16);
}

// LDS elem index for transposed tile xT[p][c] (bf16, PT rows of 64 c).
// 8-c granules XOR'd by (p&7): ds_write_b64 of 4 contig c stays intact and
// ds_read_b128 of 8 contig c stays intact; banks spread across granules.
// Round-2 measured 2.05M conflict-cy with this key vs 4.1M with (p>>2)&7
// -> keep (p&7).
static __device__ __forceinline__ int lds_x(int p, int c) {
    return p * 64 + ((((c >> 3) ^ (p & 7)) << 3) | (c & 7));
}

// ---- K0: zero the S/qq/kk accumulators (they live at head of d_out) ----
__global__ void k_zero(float* acc) {
    int i = blockIdx.x * 256 + threadIdx.x;
    if (i < 2700) acc[i] = 0.f;   // S 2500 + qq 100 + kk 100
}

// ---- Kw: split all 192 W rows into bf16 hi/lo (native layout). ----
__global__ void k_wprep(const float* __restrict__ W) {
    int i = blockIdx.x * 256 + threadIdx.x;          // over 192*64
    if (i < 128 * 64) {
        float w = W[i];                              // W[d'][c], native index
        ushort_t hi = f2bf(w);
        g_Wthi[i] = hi;
        g_Wtlo[i] = f2bf(w - bf2f(hi));
    } else if (i < 192 * 64) {
        float w = W[i];                              // v rows 128..191
        int j = i - 128 * 64;
        ushort_t hi = f2bf(w);
        g_Wvhi[j] = hi;
        g_Wvlo[j] = f2bf(w - bf2f(hi));
    }
}

// ---- K1: Q,K projection via compensated-bf16 MFMA + fused norms.
// grid (HW/PT, NN, B), 256 thr = 4 waves, 32KB LDS, launch_bounds(256,4)
// -> 4 blocks/CU (16 waves/CU) with a 128-VGPR budget: round-2's per-wave
// code quality (PT=128 amortizes one A-frag load over 4 p-tiles, 48 MFMA)
// plus 2x its occupancy. Round-3's bounds(256,8) squeezed VGPRs to 32 and
// REGRESSED (131us vs 92) -- do not re-tighten.
__global__ void __launch_bounds__(256, 4)
k_qkmfma(const float* __restrict__ x,
         ushort_t* __restrict__ Q, ushort_t* __restrict__ K,
         float* __restrict__ qq, float* __restrict__ kk) {
    __shared__ ushort_t sXhi[PT * 64];
    __shared__ ushort_t sXlo[PT * 64];

    const int t  = threadIdx.x;
    const int wv = t >> 6, ln = t & 63;
    const int n  = blockIdx.y, b = blockIdx.z;
    const int gp0 = blockIdx.x * PT;

    // ---- A fragments first (independent of LDS -> overlaps the stage).
    const int row = ln & 31, kh = (ln >> 5) * 8, d0 = wv * 32;
    short8 ahi[4], alo[4];
#pragma unroll
    for (int ks = 0; ks < 4; ++ks) {
        ahi[ks] = *(const short8*)&g_Wthi[(d0 + row) * 64 + ks * 16 + kh];
        alo[ks] = *(const short8*)&g_Wtlo[(d0 + row) * 64 + ks * 16 + kh];
    }

    // ---- stage: wave wv loads c in [wv*16, wv*16+16), converts to hi/lo,
    // writes transposed into LDS. Global loads: 64 lanes x 4B contiguous.
    {
        const int c16 = wv * 16;
#pragma unroll
        for (int cg = 0; cg < 4; ++cg) {
            const int c4 = c16 + cg * 4;
            const float* xc = x + ((size_t)(b * C + c4) * NN + n) * HW + gp0;
#pragma unroll
            for (int ph = 0; ph < 2; ++ph) {
                const int p = ph * 64 + ln;
                float v[4];
#pragma unroll
                for (int i = 0; i < 4; ++i) v[i] = xc[(size_t)i * NN * HW + p];
                us4 h, l;
#pragma unroll
                for (int i = 0; i < 4; ++i) {
                    ushort_t hi = f2bf(v[i]);
                    h[i] = hi;
                    l[i] = f2bf(v[i] - bf2f(hi));
                }
                *(us4*)&sXhi[lds_x(p, c4)] = h;
                *(us4*)&sXlo[lds_x(p, c4)] = l;
            }
        }
    }
    __syncthreads();

    ushort_t* __restrict__ O = (wv < 2) ? Q : K;
    const int dbase = (wv < 2) ? d0 : (d0 - 64);
    const size_t obase = ((size_t)(b * NN + n) * D + dbase) * HW + gp0;

    float nrm = 0.f;
#pragma unroll
    for (int pt = 0; pt < 4; ++pt) {
        const int pcol = pt * 32 + row;
        floatx16 acc;
#pragma unroll
        for (int r = 0; r < 16; ++r) acc[r] = 0.f;
#pragma unroll
        for (int ks = 0; ks < 4; ++ks) {
            const int c0 = ks * 16 + kh;
            short8 bhi = *(const short8*)&sXhi[lds_x(pcol, c0)];
            short8 blo = *(const short8*)&sXlo[lds_x(pcol, c0)];
            acc = __builtin_amdgcn_mfma_f32_32x32x16_bf16(ahi[ks], bhi, acc, 0, 0, 0);
            acc = __builtin_amdgcn_mfma_f32_32x32x16_bf16(alo[ks], bhi, acc, 0, 0, 0);
            acc = __builtin_amdgcn_mfma_f32_32x32x16_bf16(ahi[ks], blo, acc, 0, 0, 0);
        }
        // C/D layout (m74/m101): col = ln&31, row = (r&3)+8*(r>>2)+4*(ln>>5)
#pragma unroll
        for (int r = 0; r < 16; ++r) {
            const int dr = (r & 3) + 8 * (r >> 2) + 4 * (ln >> 5);
            nrm += acc[r] * acc[r];
            O[obase + (size_t)dr * HW + pcol] = f2bf(acc[r]);
        }
    }
    for (int off = 32; off > 0; off >>= 1) nrm += __shfl_xor(nrm, off);
    if (ln == 0) atomicAdd(((wv < 2) ? qq : kk) + b * NN + n, nrm);
}

// ---- K2: S[n][m] += sum_f Q[n,f]*K[m,f] via one 32x32x16 bf16 MFMA tile.
// grid (F/(4*SW), B), 256 thr = 4 waves, each wave owns SW f-elems.
__global__ void k_sqk(const ushort_t* __restrict__ Q, const ushort_t* __restrict__ K,
                      float* __restrict__ S) {
    const int t  = threadIdx.x;
    const int wv = t >> 6, ln = t & 63;
    const int b  = blockIdx.y;
    const int row  = ln & 31;
    const int rowc = (row < NN) ? row : (NN - 1);   // clamp pad rows
    const int kh   = (ln >> 5) * 8;                 // k-half offset
    const size_t f0 = (size_t)blockIdx.x * (4 * SW) + (size_t)wv * SW;
    const ushort_t* Qp = Q + ((size_t)b * NN + rowc) * F + f0 + kh;
    const ushort_t* Kp = K + ((size_t)b * NN + rowc) * F + f0 + kh;

    floatx16 acc;
#pragma unroll
    for (int r = 0; r < 16; ++r) acc[r] = 0.f;

    for (int s = 0; s < SW / 16; ++s) {
        short8 aq = *(const short8*)(Qp + s * 16);  // A[row][k] : 8 contig bf16
        short8 bk = *(const short8*)(Kp + s * 16);  // B[k][col] : K row 'col'
        acc = __builtin_amdgcn_mfma_f32_32x32x16_bf16(aq, bk, acc, 0, 0, 0);
    }

    // cross-wave reduce in LDS (stride 17 -> conflict-free), then atomics
    __shared__ float redS[4][64][17];
#pragma unroll
    for (int r = 0; r < 16; ++r) redS[wv][ln][r] = acc[r];
    __syncthreads();
    if (wv == 0) {
#pragma unroll
        for (int r = 0; r < 16; ++r) {
            float v = redS[0][ln][r] + redS[1][ln][r] + redS[2][ln][r] + redS[3][ln][r];
            const int srow = (r & 3) + 8 * (r >> 2) + 4 * (ln >> 5); // C/D: m74/m101
            const int scol = ln & 31;
            if (srow < NN && scol < NN)
                atomicAdd(&S[((size_t)b * NN + srow) * NN + scol], v);
        }
    }
}

// ---- K3: normalize logits + softmax over m; writes TRANSPOSED att.
__global__ void k_softmax(const float* __restrict__ S, const float* __restrict__ qq,
                          const float* __restrict__ kk, float* __restrict__ attT) {
    const int b = blockIdx.x, n = threadIdx.x;
    if (n >= NN) return;
    const float qn = fmaxf(sqrtf(qq[b * NN + n]), 1e-12f);
    float l[NN], mx = -1e30f;
#pragma unroll
    for (int m = 0; m < NN; ++m) {
        const float km = fmaxf(sqrtf(kk[b * NN + m]), 1e-12f);
        l[m] = S[((size_t)b * NN + n) * NN + m] / (qn * km);
        mx = fmaxf(mx, l[m]);
    }
    float s = 0.f;
#pragma unroll
    for (int m = 0; m < NN; ++m) { l[m] = expf(l[m] - mx); s += l[m]; }
    const float inv = 1.f / s;
#pragma unroll
    for (int m = 0; m < NN; ++m) attT[((size_t)b * NN + m) * NN + n] = l[m] * inv;
}

// ---- K4a: xa[b,c,n,p] = sum_m att[n,m] * x[b,c,m,p], f32x4 form.
// grid (HW/1024, C, B) = 1024 blocks (4/CU resident). 4 p per thread:
// 4 FMA per loaded element, acc = 25 x f32x4 = 100 VGPR.
__global__ void __launch_bounds__(256, 4)
k_mix(const float* __restrict__ x, const float* __restrict__ attT,
      float* __restrict__ xa) {
    const int p = (blockIdx.x * 256 + threadIdx.x) * 4;
    const int c = blockIdx.y, b = blockIdx.z;
    const float* xb = x + ((size_t)(b * C + c) * NN) * HW + p;
    const float* at = attT + (size_t)b * NN * NN;
    f32x4 acc[NN];
#pragma unroll
    for (int n = 0; n < NN; ++n) acc[n] = 0.f;
#pragma unroll 5
    for (int m = 0; m < NN; ++m) {
        const f32x4 xm = *(const f32x4*)(xb + (size_t)m * HW);
#pragma unroll
        for (int n = 0; n < NN; ++n) acc[n] += at[m * NN + n] * xm; // contig s_load
    }
#pragma unroll
    for (int n = 0; n < NN; ++n)
        *(f32x4*)&xa[((size_t)(b * C + c) * NN + n) * HW + p] = acc[n];
}

// ---- K4b: out[b,d,n,p] = sum_c Wv[d,c]*xa[b,c,n,p] via compensated MFMA.
// Clone of k_qkmfma's structure at PT=128 / bounds(256,4): wave wv owns
// d-slab (wv&1)*32 and p-half (wv>>1); 2 p-tiles x 4 ks x 3 = 24 MFMA.
// fp32 stores, 128B contiguous per instr.
__global__ void __launch_bounds__(256, 4)
k_vproj(const float* __restrict__ xa, float* __restrict__ out) {
    __shared__ ushort_t sXhi[PT * 64];
    __shared__ ushort_t sXlo[PT * 64];

    const int t  = threadIdx.x;
    const int wv = t >> 6, ln = t & 63;
    const int n  = blockIdx.y, b = blockIdx.z;
    const int gp0 = blockIdx.x * PT;

    const int row = ln & 31, kh = (ln >> 5) * 8;
    const int d0  = (wv & 1) * 32;
    short8 ahi[4], alo[4];
#pragma unroll
    for (int ks = 0; ks < 4; ++ks) {
        ahi[ks] = *(const short8*)&g_Wvhi[(d0 + row) * 64 + ks * 16 + kh];
        alo[ks] = *(const short8*)&g_Wvlo[(d0 + row) * 64 + ks * 16 + kh];
    }

    {
        const int c16 = wv * 16;
#pragma unroll
        for (int cg = 0; cg < 4; ++cg) {
            const int c4 = c16 + cg * 4;
            const float* xc = xa + ((size_t)(b * C + c4) * NN + n) * HW + gp0;
#pragma unroll
            for (int ph = 0; ph < 2; ++ph) {
                const int p = ph * 64 + ln;
                float v[4];
#pragma unroll
                for (int i = 0; i < 4; ++i) v[i] = xc[(size_t)i * NN * HW + p];
                us4 h, l;
#pragma unroll
                for (int i = 0; i < 4; ++i) {
                    ushort_t hi = f2bf(v[i]);
                    h[i] = hi;
                    l[i] = f2bf(v[i] - bf2f(hi));
                }
                *(us4*)&sXhi[lds_x(p, c4)] = h;
                *(us4*)&sXlo[lds_x(p, c4)] = l;
            }
        }
    }
    __syncthreads();

    const int ph0 = (wv >> 1) * 64;
#pragma unroll
    for (int pt = 0; pt < 2; ++pt) {
        const int pcol = ph0 + pt * 32 + row;
        floatx16 acc;
#pragma unroll
        for (int r = 0; r < 16; ++r) acc[r] = 0.f;
#pragma unroll
        for (int ks = 0; ks < 4; ++ks) {
            const int c0 = ks * 16 + kh;
            short8 bhi = *(const short8*)&sXhi[lds_x(pcol, c0)];
            short8 blo = *(const short8*)&sXlo[lds_x(pcol, c0)];
            acc = __builtin_amdgcn_mfma_f32_32x32x16_bf16(ahi[ks], bhi, acc, 0, 0, 0);
            acc = __builtin_amdgcn_mfma_f32_32x32x16_bf16(alo[ks], bhi, acc, 0, 0, 0);
            acc = __builtin_amdgcn_mfma_f32_32x32x16_bf16(ahi[ks], blo, acc, 0, 0, 0);
        }
#pragma unroll
        for (int r = 0; r < 16; ++r) {
            const int dr = (r & 3) + 8 * (r >> 2) + 4 * (ln >> 5);
            out[((size_t)(b * D + d0 + dr) * NN + n) * HW + gp0 + pcol] = acc[r];
        }
    }
}

extern "C" void kernel_launch(void* const* d_in, const int* in_sizes, int n_in,
                              void* d_out, int out_size, void* d_ws, size_t ws_size,
                              hipStream_t stream) {
    const float* x = (const float*)d_in[0];
    const float* W = (const float*)d_in[1];
    float* outf = (float*)d_out;

    // ws: [ Q bf16 52.4MB | K bf16 52.4MB ], later reused as xa fp32 (104.86MB)
    ushort_t* Q  = (ushort_t*)d_ws;
    ushort_t* K  = Q + (size_t)B * NN * F;
    float*    xa = (float*)d_ws;

    // tiny accumulators live at head of d_out (dead until k_vproj rewrites all)
    float* S    = outf;          // 4*25*25
    float* qq   = outf + 2500;   // 4*25
    float* kk   = outf + 2600;   // 4*25
    float* attT = outf + 2700;   // 4*25*25 (transposed: [b][m][n])

    k_zero   <<<dim3(11),             256, 0, stream>>>(outf);
    k_wprep  <<<dim3(48),             256, 0, stream>>>(W);
    k_qkmfma <<<dim3(HW/PT, NN, B),   256, 0, stream>>>(x, Q, K, qq, kk);
    k_sqk    <<<dim3(F/(4*SW), B),    256, 0, stream>>>(Q, K, S);
    k_softmax<<<dim3(B),               64, 0, stream>>>(S, qq, kk, attT);
    k_mix    <<<dim3(HW/1024, C, B),  256, 0, stream>>>(x, attT, xa);
    k_vproj  <<<dim3(HW/PT, NN, B),   256, 0, stream>>>(xa, outf);
}

// Round 5
// 309.747 us; speedup vs baseline: 1.1850x; 1.0189x over previous
//
#include <hip/hip_runtime.h>

// Problem constants (fixed by reference setup_inputs)
#define B   4
#define C   64      // input channels
#define D   64      // dims per head of q/k/v
#define NN  25      // angRes*angRes angular positions
#define HW  4096    // h*w
#define F   (D*HW)  // 262144 feature dim per head, flattened

#define SW  256     // f elems per wave in k_sqk (4 waves/block) -> 1024 blocks
#define PT  128     // p-tile per block in k_proj (32KB LDS, 4 blk/CU)

typedef unsigned short ushort_t;
typedef unsigned int   uint_t;
typedef __attribute__((ext_vector_type(8)))  short  short8;   // 8 bf16 (4 VGPRs)
typedef __attribute__((ext_vector_type(16))) float  floatx16; // MFMA 32x32 accum
typedef __attribute__((ext_vector_type(4)))  float  f32x4;
typedef __attribute__((ext_vector_type(4)))  unsigned short us4;

// Compensated bf16 weight splits (W = hi + lo, |err| ~ 2^-17 rel), native
// [row][c] layout. Rows 0..127 = q,k; Wv rows 0..63 = v.
__device__ ushort_t g_Wthi[128 * C];
__device__ ushort_t g_Wtlo[128 * C];
__device__ ushort_t g_Wvhi[D * C];
__device__ ushort_t g_Wvlo[D * C];

// Tiny cross-kernel accumulators (20KB) -- frees d_out to host Q,K.
__device__ float g_S[B * NN * NN];
__device__ float g_qq[B * NN];
__device__ float g_kk[B * NN];
__device__ float g_attT[B * NN * NN];   // transposed att [b][m][n]

static __device__ __forceinline__ ushort_t f2bf(float f) {
    uint_t u = __float_as_uint(f);
    u += 0x7FFFu + ((u >> 16) & 1u);   // round-to-nearest-even
    return (ushort_t)(u >> 16);
}
static __device__ __forceinline__ float bf2f(ushort_t h) {
    return __uint_as_float((uint_t)h << 16);
}

// LDS elem index for transposed tile xT[p][c] (bf16, PT rows of 64 c).
// 8-c granules XOR'd by (p&7) -- measured best (2.05M conflict-cy vs 4.1M
// for (p>>2)&7). ds_write_b64 (4c) and ds_read_b128 (8c) stay intact.
static __device__ __forceinline__ int lds_x(int p, int c) {
    return p * 64 + ((((c >> 3) ^ (p & 7)) << 3) | (c & 7));
}

// ---- K0: zero S/qq/kk ----
__global__ void k_zero() {
    int i = blockIdx.x * 256 + threadIdx.x;
    if (i < 2500)      g_S[i] = 0.f;
    else if (i < 2600) g_qq[i - 2500] = 0.f;
    else if (i < 2700) g_kk[i - 2600] = 0.f;
}

// ---- Kw: split all 192 W rows into bf16 hi/lo (native layout). ----
__global__ void k_wprep(const float* __restrict__ W) {
    int i = blockIdx.x * 256 + threadIdx.x;          // over 192*64
    if (i < 128 * 64) {
        float w = W[i];                              // W[d'][c], native index
        ushort_t hi = f2bf(w);
        g_Wthi[i] = hi;
        g_Wtlo[i] = f2bf(w - bf2f(hi));
    } else if (i < 192 * 64) {
        float w = W[i];                              // v rows 128..191
        int j = i - 128 * 64;
        ushort_t hi = f2bf(w);
        g_Wvhi[j] = hi;
        g_Wvlo[j] = f2bf(w - bf2f(hi));
    }
}

// ---- K1: fused Q,K,V projection via compensated-bf16 MFMA + fused norms.
// grid (HW/PT, NN, B), 256 thr = 4 waves, 32KB LDS, bounds(256,4).
// Wave wv: QK slab d0=wv*32 over 4 p-tiles (48 MFMA), then V slab
// sv=(wv&1)*32 over p-half ph=wv>>1 (24 MFMA). x staged ONCE feeds all
// 192 projection rows (was staged twice across k_qkmfma+k_mix).
//
// Q/K/V are stored PACKED in MFMA C/D order (layout is ours; k_sqk treats
// f as an opaque enumeration, k_outmix decodes at the end):
//   Q/K elem f = [tile(32)][slab(2)][pt(4)][r4(4)][ln(64)][j(4)]
//   V   elem g = [tile(32)][sv(2)][ph(2)][pt(2)][r4(4)][ln(64)][j(4)]
// -> epilogue stores are us4 (8B/lane, 512B/instr) and f32x4 (1KB/instr)
// instead of 64 scalar 2B stores (128B/instr) + per-store address math.
__global__ void __launch_bounds__(256, 4)
k_proj(const float* __restrict__ x,
       ushort_t* __restrict__ Q, ushort_t* __restrict__ K,
       float* __restrict__ V) {
    __shared__ ushort_t sXhi[PT * 64];
    __shared__ ushort_t sXlo[PT * 64];

    const int t  = threadIdx.x;
    const int wv = t >> 6, ln = t & 63;
    const int n  = blockIdx.y, b = blockIdx.z;
    const int tile = blockIdx.x;
    const int gp0  = tile * PT;

    // ---- QK A-fragments first (independent of LDS -> overlap the stage).
    const int row = ln & 31, kh = (ln >> 5) * 8, d0 = wv * 32;
    short8 ahi[4], alo[4];
#pragma unroll
    for (int ks = 0; ks < 4; ++ks) {
        ahi[ks] = *(const short8*)&g_Wthi[(d0 + row) * 64 + ks * 16 + kh];
        alo[ks] = *(const short8*)&g_Wtlo[(d0 + row) * 64 + ks * 16 + kh];
    }

    // ---- stage: wave wv loads c in [wv*16, wv*16+16), hi/lo, transposed.
    {
        const int c16 = wv * 16;
#pragma unroll
        for (int cg = 0; cg < 4; ++cg) {
            const int c4 = c16 + cg * 4;
            const float* xc = x + ((size_t)(b * C + c4) * NN + n) * HW + gp0;
#pragma unroll
            for (int ph = 0; ph < 2; ++ph) {
                const int p = ph * 64 + ln;
                float v[4];
#pragma unroll
                for (int i = 0; i < 4; ++i) v[i] = xc[(size_t)i * NN * HW + p];
                us4 h, l;
#pragma unroll
                for (int i = 0; i < 4; ++i) {
                    ushort_t hi = f2bf(v[i]);
                    h[i] = hi;
                    l[i] = f2bf(v[i] - bf2f(hi));
                }
                *(us4*)&sXhi[lds_x(p, c4)] = h;
                *(us4*)&sXlo[lds_x(p, c4)] = l;
            }
        }
    }
    __syncthreads();

    // ---- QK phase: 4 p-tiles, packed epilogue stores.
    ushort_t* __restrict__ O = (wv < 2) ? Q : K;
    const int slab = (wv < 2) ? wv : wv - 2;
    const size_t nbase = (size_t)(b * NN + n) * F;

    float nrm = 0.f;
#pragma unroll
    for (int pt = 0; pt < 4; ++pt) {
        const int pcol = pt * 32 + row;
        floatx16 acc;
#pragma unroll
        for (int r = 0; r < 16; ++r) acc[r] = 0.f;
#pragma unroll
        for (int ks = 0; ks < 4; ++ks) {
            const int c0 = ks * 16 + kh;
            short8 bhi = *(const short8*)&sXhi[lds_x(pcol, c0)];
            short8 blo = *(const short8*)&sXlo[lds_x(pcol, c0)];
            acc = __builtin_amdgcn_mfma_f32_32x32x16_bf16(ahi[ks], bhi, acc, 0, 0, 0);
            acc = __builtin_amdgcn_mfma_f32_32x32x16_bf16(alo[ks], bhi, acc, 0, 0, 0);
            acc = __builtin_amdgcn_mfma_f32_32x32x16_bf16(ahi[ks], blo, acc, 0, 0, 0);
        }
#pragma unroll
        for (int r4 = 0; r4 < 4; ++r4) {
            us4 h;
#pragma unroll
            for (int j = 0; j < 4; ++j) {
                const float a = acc[r4 * 4 + j];
                nrm += a * a;
                h[j] = f2bf(a);
            }
            *(us4*)&O[nbase + (((size_t)((tile * 2 + slab) * 16 + pt * 4 + r4)) << 8)
                      + ln * 4] = h;
        }
    }
    for (int off = 32; off > 0; off >>= 1) nrm += __shfl_xor(nrm, off);
    if (ln == 0) atomicAdd(((wv < 2) ? g_qq : g_kk) + b * NN + n, nrm);

    // ---- V phase: slab sv, p-half ph; fp32 packed stores.
    {
        const int sv = wv & 1, ph = wv >> 1;
        short8 vhi[4], vlo[4];
#pragma unroll
        for (int ks = 0; ks < 4; ++ks) {
            vhi[ks] = *(const short8*)&g_Wvhi[(sv * 32 + row) * 64 + ks * 16 + kh];
            vlo[ks] = *(const short8*)&g_Wvlo[(sv * 32 + row) * 64 + ks * 16 + kh];
        }
#pragma unroll
        for (int pt = 0; pt < 2; ++pt) {
            const int pcol = ph * 64 + pt * 32 + row;
            floatx16 acc;
#pragma unroll
            for (int r = 0; r < 16; ++r) acc[r] = 0.f;
#pragma unroll
            for (int ks = 0; ks < 4; ++ks) {
                const int c0 = ks * 16 + kh;
                short8 bhi = *(const short8*)&sXhi[lds_x(pcol, c0)];
                short8 blo = *(const short8*)&sXlo[lds_x(pcol, c0)];
                acc = __builtin_amdgcn_mfma_f32_32x32x16_bf16(vhi[ks], bhi, acc, 0, 0, 0);
                acc = __builtin_amdgcn_mfma_f32_32x32x16_bf16(vlo[ks], bhi, acc, 0, 0, 0);
                acc = __builtin_amdgcn_mfma_f32_32x32x16_bf16(vhi[ks], blo, acc, 0, 0, 0);
            }
#pragma unroll
            for (int r4 = 0; r4 < 4; ++r4) {
                f32x4 o;
#pragma unroll
                for (int j = 0; j < 4; ++j) o[j] = acc[r4 * 4 + j];
                V[nbase + (((size_t)((((tile * 2 + sv) * 2 + ph) * 2 + pt) * 4 + r4)) << 8)
                  + ln * 4] = o[0],
                *(f32x4*)&V[nbase + (((size_t)((((tile * 2 + sv) * 2 + ph) * 2 + pt) * 4
                  + r4)) << 8) + ln * 4] = o;
            }
        }
    }
}

// ---- K2: S[n][m] += sum_f Q[n,f]*K[m,f] via one 32x32x16 bf16 MFMA tile.
// f is the packed enumeration -- identical for Q and K, so the dot product
// is unchanged. grid (F/(4*SW), B), 4 waves x SW f-elems.
__global__ void k_sqk(const ushort_t* __restrict__ Q, const ushort_t* __restrict__ K) {
    const int t  = threadIdx.x;
    const int wv = t >> 6, ln = t & 63;
    const int b  = blockIdx.y;
    const int row  = ln & 31;
    const int rowc = (row < NN) ? row : (NN - 1);   // clamp pad rows
    const int kh   = (ln >> 5) * 8;                 // k-half offset
    const size_t f0 = (size_t)blockIdx.x * (4 * SW) + (size_t)wv * SW;
    const ushort_t* Qp = Q + ((size_t)b * NN + rowc) * F + f0 + kh;
    const ushort_t* Kp = K + ((size_t)b * NN + rowc) * F + f0 + kh;

    floatx16 acc;
#pragma unroll
    for (int r = 0; r < 16; ++r) acc[r] = 0.f;

    for (int s = 0; s < SW / 16; ++s) {
        short8 aq = *(const short8*)(Qp + s * 16);  // A[row][k] : 8 contig bf16
        short8 bk = *(const short8*)(Kp + s * 16);  // B[k][col] : K row 'col'
        acc = __builtin_amdgcn_mfma_f32_32x32x16_bf16(aq, bk, acc, 0, 0, 0);
    }

    // cross-wave reduce in LDS (stride 17 -> conflict-free), then atomics
    __shared__ float redS[4][64][17];
#pragma unroll
    for (int r = 0; r < 16; ++r) redS[wv][ln][r] = acc[r];
    __syncthreads();
    if (wv == 0) {
#pragma unroll
        for (int r = 0; r < 16; ++r) {
            float v = redS[0][ln][r] + redS[1][ln][r] + redS[2][ln][r] + redS[3][ln][r];
            const int srow = (r & 3) + 8 * (r >> 2) + 4 * (ln >> 5); // C/D: m74/m101
            const int scol = ln & 31;
            if (srow < NN && scol < NN)
                atomicAdd(&g_S[((size_t)b * NN + srow) * NN + scol], v);
        }
    }
}

// ---- K3: normalize logits + softmax over m; writes TRANSPOSED att.
__global__ void k_softmax() {
    const int b = blockIdx.x, n = threadIdx.x;
    if (n >= NN) return;
    const float qn = fmaxf(sqrtf(g_qq[b * NN + n]), 1e-12f);
    float l[NN], mx = -1e30f;
#pragma unroll
    for (int m = 0; m < NN; ++m) {
        const float km = fmaxf(sqrtf(g_kk[b * NN + m]), 1e-12f);
        l[m] = g_S[((size_t)b * NN + n) * NN + m] / (qn * km);
        mx = fmaxf(mx, l[m]);
    }
    float s = 0.f;
#pragma unroll
    for (int m = 0; m < NN; ++m) { l[m] = expf(l[m] - mx); s += l[m]; }
    const float inv = 1.f / s;
#pragma unroll
    for (int m = 0; m < NN; ++m) g_attT[((size_t)b * NN + m) * NN + n] = l[m] * inv;
}

// ---- K4: out[b,d,n,p] = sum_m att[n,m] * V[b,m,(d,p)], packed-V form.
// grid (F/1024, B) = 1024 blocks. Thread owns 4 consecutive packed g
// (= one lane-chunk of a k_proj store): f32x4 loads fully coalesced
// (1KB/instr); acc = 25 x f32x4. (d,p) decoded only for the final store.
__global__ void __launch_bounds__(256, 4)
k_outmix(const float* __restrict__ V, float* __restrict__ out) {
    const int tid = blockIdx.x * 256 + threadIdx.x;   // 0..65535 per b
    const int b   = blockIdx.y;
    const float* Vb = V + (size_t)b * NN * F + (size_t)tid * 4;
    const float* at = g_attT + b * NN * NN;

    f32x4 acc[NN];
#pragma unroll
    for (int n = 0; n < NN; ++n) acc[n] = 0.f;
#pragma unroll 5
    for (int m = 0; m < NN; ++m) {
        const f32x4 v = *(const f32x4*)(Vb + (size_t)m * F);
#pragma unroll
        for (int n = 0; n < NN; ++n) acc[n] += at[m * NN + n] * v;
    }

    // decode packed g -> (d,p): g chunk = [tile][sv][ph][pt][r4], lane=ln
    const int ln = tid & 63, c0 = tid >> 6;
    const int r4 = c0 & 3, pt = (c0 >> 2) & 1, ph = (c0 >> 3) & 1;
    const int sv = (c0 >> 4) & 1, tile = c0 >> 5;
    const int p  = tile * 128 + ph * 64 + pt * 32 + (ln & 31);
    const int db = sv * 32 + 8 * r4 + 4 * (ln >> 5);  // rows db..db+3 (j)
#pragma unroll
    for (int n = 0; n < NN; ++n)
#pragma unroll
        for (int j = 0; j < 4; ++j)
            out[((size_t)(b * D + db + j) * NN + n) * HW + p] = acc[n][j];
}

extern "C" void kernel_launch(void* const* d_in, const int* in_sizes, int n_in,
                              void* d_out, int out_size, void* d_ws, size_t ws_size,
                              hipStream_t stream) {
    const float* x = (const float*)d_in[0];
    const float* W = (const float*)d_in[1];
    float* outf = (float*)d_out;

    // Q+K bf16 = 104,857,600 B = exactly out_size -> live in d_out (dead
    // before k_outmix rewrites it). V fp32 = 104,857,600 B -> d_ws (the old
    // xa footprint). S/qq/kk/attT are __device__ globals.
    ushort_t* Q = (ushort_t*)d_out;
    ushort_t* K = Q + (size_t)B * NN * F;
    float*    V = (float*)d_ws;

    k_zero   <<<dim3(11),           256, 0, stream>>>();
    k_wprep  <<<dim3(48),           256, 0, stream>>>(W);
    k_proj   <<<dim3(HW/PT, NN, B), 256, 0, stream>>>(x, Q, K, V);
    k_sqk    <<<dim3(F/(4*SW), B),  256, 0, stream>>>(Q, K);
    k_softmax<<<dim3(B),             64, 0, stream>>>();
    k_outmix <<<dim3(F/1024, B),    256, 0, stream>>>(V, outf);
}

// Round 6
// 302.889 us; speedup vs baseline: 1.2118x; 1.0226x over previous
//
#include <hip/hip_runtime.h>

// Problem constants (fixed by reference setup_inputs)
#define B   4
#define C   64      // input channels
#define D   64      // dims per head of q/k/v
#define NN  25      // angRes*angRes angular positions
#define HW  4096    // h*w
#define F   (D*HW)  // 262144 feature dim per head, flattened

#define PT  128     // p-tile per block in k_proj (32KB LDS, 4 blk/CU)
#define QCH 256     // f elems staged per chunk in k_sqk
#define NCH 4       // chunks per k_sqk block -> block covers 1024 f

typedef unsigned short ushort_t;
typedef unsigned int   uint_t;
typedef __attribute__((ext_vector_type(8)))  short  short8;   // 8 bf16 (4 VGPRs)
typedef __attribute__((ext_vector_type(8)))  unsigned short us8;
typedef __attribute__((ext_vector_type(16))) float  floatx16; // MFMA 32x32 accum
typedef __attribute__((ext_vector_type(4)))  float  f32x4;
typedef __attribute__((ext_vector_type(4)))  unsigned short us4;

// Compensated bf16 weight splits (W = hi + lo, |err| ~ 2^-17 rel), native
// [row][c] layout. Rows 0..127 = q,k; Wv rows 0..63 = v.
__device__ ushort_t g_Wthi[128 * C];
__device__ ushort_t g_Wtlo[128 * C];
__device__ ushort_t g_Wvhi[D * C];
__device__ ushort_t g_Wvlo[D * C];

// Tiny cross-kernel accumulators (20KB) -- frees d_out to host Q,K.
__device__ float g_S[B * NN * NN];
__device__ float g_qq[B * NN];
__device__ float g_kk[B * NN];
__device__ float g_attT[B * NN * NN];   // transposed att [b][m][n]

static __device__ __forceinline__ ushort_t f2bf(float f) {
    uint_t u = __float_as_uint(f);
    u += 0x7FFFu + ((u >> 16) & 1u);   // round-to-nearest-even
    return (ushort_t)(u >> 16);
}
static __device__ __forceinline__ float bf2f(ushort_t h) {
    return __uint_as_float((uint_t)h << 16);
}

// LDS elem index for transposed tile xT[p][c] (bf16, PT rows of 64 c).
// 8-c granules XOR'd by (p&7) -- measured best (2.05M conflict-cy vs 4.1M
// for (p>>2)&7). ds_write_b64 (4c) and ds_read_b128 (8c) stay intact.
static __device__ __forceinline__ int lds_x(int p, int c) {
    return p * 64 + ((((c >> 3) ^ (p & 7)) << 3) | (c & 7));
}

// ---- K0: zero S/qq/kk ----
__global__ void k_zero() {
    int i = blockIdx.x * 256 + threadIdx.x;
    if (i < 2500)      g_S[i] = 0.f;
    else if (i < 2600) g_qq[i - 2500] = 0.f;
    else if (i < 2700) g_kk[i - 2600] = 0.f;
}

// ---- Kw: split all 192 W rows into bf16 hi/lo (native layout). ----
__global__ void k_wprep(const float* __restrict__ W) {
    int i = blockIdx.x * 256 + threadIdx.x;          // over 192*64
    if (i < 128 * 64) {
        float w = W[i];                              // W[d'][c], native index
        ushort_t hi = f2bf(w);
        g_Wthi[i] = hi;
        g_Wtlo[i] = f2bf(w - bf2f(hi));
    } else if (i < 192 * 64) {
        float w = W[i];                              // v rows 128..191
        int j = i - 128 * 64;
        ushort_t hi = f2bf(w);
        g_Wvhi[j] = hi;
        g_Wvlo[j] = f2bf(w - bf2f(hi));
    }
}

// ---- K1: fused Q,K,V projection via compensated-bf16 MFMA + fused norms.
// grid (HW/PT, NN, B), 256 thr = 4 waves, 32KB LDS, bounds(256,4).
// Wave wv: QK slab d0=wv*32 over 4 p-tiles (48 MFMA), then V slab
// sv=(wv&1)*32 over p-half ph=wv>>1 (24 MFMA). x staged ONCE feeds all
// 192 projection rows.
// Q/K/V stored PACKED in MFMA C/D order (f is an opaque enumeration to
// k_sqk; k_outmix decodes (d,p) at the end):
//   Q/K elem f = [tile(32)][slab(2)][pt(4)][r4(4)][ln(64)][j(4)]
//   V   elem g = [tile(32)][sv(2)][ph(2)][pt(2)][r4(4)][ln(64)][j(4)]
__global__ void __launch_bounds__(256, 4)
k_proj(const float* __restrict__ x,
       ushort_t* __restrict__ Q, ushort_t* __restrict__ K,
       float* __restrict__ V) {
    __shared__ ushort_t sXhi[PT * 64];
    __shared__ ushort_t sXlo[PT * 64];

    const int t  = threadIdx.x;
    const int wv = t >> 6, ln = t & 63;
    const int n  = blockIdx.y, b = blockIdx.z;
    const int tile = blockIdx.x;
    const int gp0  = tile * PT;

    // ---- QK A-fragments first (independent of LDS -> overlap the stage).
    const int row = ln & 31, kh = (ln >> 5) * 8, d0 = wv * 32;
    short8 ahi[4], alo[4];
#pragma unroll
    for (int ks = 0; ks < 4; ++ks) {
        ahi[ks] = *(const short8*)&g_Wthi[(d0 + row) * 64 + ks * 16 + kh];
        alo[ks] = *(const short8*)&g_Wtlo[(d0 + row) * 64 + ks * 16 + kh];
    }

    // ---- stage: wave wv loads c in [wv*16, wv*16+16), hi/lo, transposed.
    {
        const int c16 = wv * 16;
#pragma unroll
        for (int cg = 0; cg < 4; ++cg) {
            const int c4 = c16 + cg * 4;
            const float* xc = x + ((size_t)(b * C + c4) * NN + n) * HW + gp0;
#pragma unroll
            for (int ph = 0; ph < 2; ++ph) {
                const int p = ph * 64 + ln;
                float v[4];
#pragma unroll
                for (int i = 0; i < 4; ++i) v[i] = xc[(size_t)i * NN * HW + p];
                us4 h, l;
#pragma unroll
                for (int i = 0; i < 4; ++i) {
                    ushort_t hi = f2bf(v[i]);
                    h[i] = hi;
                    l[i] = f2bf(v[i] - bf2f(hi));
                }
                *(us4*)&sXhi[lds_x(p, c4)] = h;
                *(us4*)&sXlo[lds_x(p, c4)] = l;
            }
        }
    }
    __syncthreads();

    // ---- QK phase: 4 p-tiles, packed epilogue stores.
    ushort_t* __restrict__ O = (wv < 2) ? Q : K;
    const int slab = (wv < 2) ? wv : wv - 2;
    const size_t nbase = (size_t)(b * NN + n) * F;

    float nrm = 0.f;
#pragma unroll
    for (int pt = 0; pt < 4; ++pt) {
        const int pcol = pt * 32 + row;
        floatx16 acc;
#pragma unroll
        for (int r = 0; r < 16; ++r) acc[r] = 0.f;
#pragma unroll
        for (int ks = 0; ks < 4; ++ks) {
            const int c0 = ks * 16 + kh;
            short8 bhi = *(const short8*)&sXhi[lds_x(pcol, c0)];
            short8 blo = *(const short8*)&sXlo[lds_x(pcol, c0)];
            acc = __builtin_amdgcn_mfma_f32_32x32x16_bf16(ahi[ks], bhi, acc, 0, 0, 0);
            acc = __builtin_amdgcn_mfma_f32_32x32x16_bf16(alo[ks], bhi, acc, 0, 0, 0);
            acc = __builtin_amdgcn_mfma_f32_32x32x16_bf16(ahi[ks], blo, acc, 0, 0, 0);
        }
#pragma unroll
        for (int r4 = 0; r4 < 4; ++r4) {
            us4 h;
#pragma unroll
            for (int j = 0; j < 4; ++j) {
                const float a = acc[r4 * 4 + j];
                nrm += a * a;
                h[j] = f2bf(a);
            }
            *(us4*)&O[nbase + (((size_t)((tile * 2 + slab) * 16 + pt * 4 + r4)) << 8)
                      + ln * 4] = h;
        }
    }
    for (int off = 32; off > 0; off >>= 1) nrm += __shfl_xor(nrm, off);
    if (ln == 0) atomicAdd(((wv < 2) ? g_qq : g_kk) + b * NN + n, nrm);

    // ---- V phase: slab sv, p-half ph; fp32 packed stores.
    {
        const int sv = wv & 1, ph = wv >> 1;
        short8 vhi[4], vlo[4];
#pragma unroll
        for (int ks = 0; ks < 4; ++ks) {
            vhi[ks] = *(const short8*)&g_Wvhi[(sv * 32 + row) * 64 + ks * 16 + kh];
            vlo[ks] = *(const short8*)&g_Wvlo[(sv * 32 + row) * 64 + ks * 16 + kh];
        }
#pragma unroll
        for (int pt = 0; pt < 2; ++pt) {
            const int pcol = ph * 64 + pt * 32 + row;
            floatx16 acc;
#pragma unroll
            for (int r = 0; r < 16; ++r) acc[r] = 0.f;
#pragma unroll
            for (int ks = 0; ks < 4; ++ks) {
                const int c0 = ks * 16 + kh;
                short8 bhi = *(const short8*)&sXhi[lds_x(pcol, c0)];
                short8 blo = *(const short8*)&sXlo[lds_x(pcol, c0)];
                acc = __builtin_amdgcn_mfma_f32_32x32x16_bf16(vhi[ks], bhi, acc, 0, 0, 0);
                acc = __builtin_amdgcn_mfma_f32_32x32x16_bf16(vlo[ks], bhi, acc, 0, 0, 0);
                acc = __builtin_amdgcn_mfma_f32_32x32x16_bf16(vhi[ks], blo, acc, 0, 0, 0);
            }
#pragma unroll
            for (int r4 = 0; r4 < 4; ++r4) {
                f32x4 o;
#pragma unroll
                for (int j = 0; j < 4; ++j) o[j] = acc[r4 * 4 + j];
                *(f32x4*)&V[nbase + (((size_t)((((tile * 2 + sv) * 2 + ph) * 2 + pt) * 4
                    + r4)) << 8) + ln * 4] = o;
            }
        }
    }
}

// ---- K2: S[n][m] += sum_f Q[n,f]*K[m,f], LDS-staged streaming reduce.
// grid (F/(QCH*NCH), B) = (256, B), 512 thr = 8 waves, bounds(512,8)
// -> 4 blk/CU, 32 waves/CU. Per chunk: stage Q[32][QCH]+K into LDS with
// COALESCED 512B-per-row loads (the old per-lane row-scatter made one
// wave-instr touch 32 separate 64B lines), XOR-swizzled (col^(row&7)) so
// the per-row ds_read_b128 fragments sit at the structural 4-way minimum.
// 8 waves x 2 MFMA/chunk cover the 16 k-steps; acc carried across chunks.
__global__ void __launch_bounds__(512, 8)
k_sqk(const ushort_t* __restrict__ Q, const ushort_t* __restrict__ K) {
    __shared__ __align__(16) unsigned char smem[35904];
    ushort_t* sQ = (ushort_t*)smem;            // [32][QCH] bf16, swizzled
    ushort_t* sK = (ushort_t*)(smem + 16384);
    float (*redS)[64][17] = (float (*)[64][17])smem;  // overlay after compute

    const int t  = threadIdx.x;
    const int wv = t >> 6, ln = t & 63;
    const int b  = blockIdx.y;
    const size_t fbase = (size_t)blockIdx.x * (QCH * NCH);

    const int col = t & 31;          // 16B unit within a 512B row
    const int r0  = t >> 5;          // 0..15 (row group)
    const int rr  = ln & 31;         // MFMA row (n for A / m for B)
    const int khalf = ln >> 5;

    floatx16 acc;
#pragma unroll
    for (int r = 0; r < 16; ++r) acc[r] = 0.f;

    for (int ch = 0; ch < NCH; ++ch) {
        const size_t f0 = fbase + (size_t)ch * QCH;
        if (ch) __syncthreads();     // protect LDS from previous readers
#pragma unroll
        for (int pass = 0; pass < 2; ++pass) {
            const int r  = pass * 16 + r0;
            const int rc = (r < NN) ? r : (NN - 1);  // clamp: L2-merged dups
            const size_t g = ((size_t)b * NN + rc) * F + f0 + col * 8;
            const int lx = r * QCH + ((col ^ (r & 7)) * 8);
            *(us8*)&sQ[lx] = *(const us8*)(Q + g);
            *(us8*)&sK[lx] = *(const us8*)(K + g);
        }
        __syncthreads();
        // wave wv owns k-steps s = wv*2 + {0,1}
#pragma unroll
        for (int i = 0; i < 2; ++i) {
            const int cunit = (wv * 2 + i) * 2 + khalf;   // 16B unit 0..31
            const int lx = rr * QCH + ((cunit ^ (rr & 7)) * 8);
            short8 aq = *(const short8*)&sQ[lx];
            short8 bk = *(const short8*)&sK[lx];
            acc = __builtin_amdgcn_mfma_f32_32x32x16_bf16(aq, bk, acc, 0, 0, 0);
        }
    }

    __syncthreads();                 // before overlaying redS on sQ/sK
#pragma unroll
    for (int r = 0; r < 16; ++r) redS[wv][ln][r] = acc[r];
    __syncthreads();
    if (wv == 0) {
#pragma unroll
        for (int r = 0; r < 16; ++r) {
            float v = 0.f;
#pragma unroll
            for (int w = 0; w < 8; ++w) v += redS[w][ln][r];
            const int srow = (r & 3) + 8 * (r >> 2) + 4 * (ln >> 5); // C/D: m74/m101
            const int scol = ln & 31;
            if (srow < NN && scol < NN)
                atomicAdd(&g_S[((size_t)b * NN + srow) * NN + scol], v);
        }
    }
}

// ---- K3: normalize logits + softmax over m; writes TRANSPOSED att.
__global__ void k_softmax() {
    const int b = blockIdx.x, n = threadIdx.x;
    if (n >= NN) return;
    const float qn = fmaxf(sqrtf(g_qq[b * NN + n]), 1e-12f);
    float l[NN], mx = -1e30f;
#pragma unroll
    for (int m = 0; m < NN; ++m) {
        const float km = fmaxf(sqrtf(g_kk[b * NN + m]), 1e-12f);
        l[m] = g_S[((size_t)b * NN + n) * NN + m] / (qn * km);
        mx = fmaxf(mx, l[m]);
    }
    float s = 0.f;
#pragma unroll
    for (int m = 0; m < NN; ++m) { l[m] = expf(l[m] - mx); s += l[m]; }
    const float inv = 1.f / s;
#pragma unroll
    for (int m = 0; m < NN; ++m) g_attT[((size_t)b * NN + m) * NN + n] = l[m] * inv;
}

// ---- K4: out[b,d,n,p] = sum_m att[n,m] * V[b,m,(d,p)], packed-V form.
// grid (F/1024, B). Thread owns 4 consecutive packed g (= one lane-chunk
// of a k_proj store): f32x4 loads fully coalesced; acc = 25 x f32x4.
// (d,p) decoded only for the final store (128B segments per half-wave).
__global__ void __launch_bounds__(256, 4)
k_outmix(const float* __restrict__ V, float* __restrict__ out) {
    const int tid = blockIdx.x * 256 + threadIdx.x;   // 0..65535 per b
    const int b   = blockIdx.y;
    const float* Vb = V + (size_t)b * NN * F + (size_t)tid * 4;
    const float* at = g_attT + b * NN * NN;

    f32x4 acc[NN];
#pragma unroll
    for (int n = 0; n < NN; ++n) acc[n] = 0.f;
#pragma unroll 5
    for (int m = 0; m < NN; ++m) {
        const f32x4 v = *(const f32x4*)(Vb + (size_t)m * F);
#pragma unroll
        for (int n = 0; n < NN; ++n) acc[n] += at[m * NN + n] * v;
    }

    // decode packed g -> (d,p): g chunk = [tile][sv][ph][pt][r4], lane=ln
    const int ln = tid & 63, c0 = tid >> 6;
    const int r4 = c0 & 3, pt = (c0 >> 2) & 1, ph = (c0 >> 3) & 1;
    const int sv = (c0 >> 4) & 1, tile = c0 >> 5;
    const int p  = tile * 128 + ph * 64 + pt * 32 + (ln & 31);
    const int db = sv * 32 + 8 * r4 + 4 * (ln >> 5);  // rows db..db+3 (j)
#pragma unroll
    for (int n = 0; n < NN; ++n)
#pragma unroll
        for (int j = 0; j < 4; ++j)
            out[((size_t)(b * D + db + j) * NN + n) * HW + p] = acc[n][j];
}

extern "C" void kernel_launch(void* const* d_in, const int* in_sizes, int n_in,
                              void* d_out, int out_size, void* d_ws, size_t ws_size,
                              hipStream_t stream) {
    const float* x = (const float*)d_in[0];
    const float* W = (const float*)d_in[1];
    float* outf = (float*)d_out;

    // Q+K bf16 = 104,857,600 B = exactly out_size -> live in d_out (dead
    // before k_outmix rewrites it). V fp32 = 104,857,600 B -> d_ws.
    ushort_t* Q = (ushort_t*)d_out;
    ushort_t* K = Q + (size_t)B * NN * F;
    float*    V = (float*)d_ws;

    k_zero   <<<dim3(11),               256, 0, stream>>>();
    k_wprep  <<<dim3(48),               256, 0, stream>>>(W);
    k_proj   <<<dim3(HW/PT, NN, B),     256, 0, stream>>>(x, Q, K, V);
    k_sqk    <<<dim3(F/(QCH*NCH), B),   512, 0, stream>>>(Q, K);
    k_softmax<<<dim3(B),                 64, 0, stream>>>();
    k_outmix <<<dim3(F/1024, B),        256, 0, stream>>>(V, outf);
}